// Round 7
// baseline (513.859 us; speedup 1.0000x reference)
//
#include <hip/hip_runtime.h>
#include <hip/hip_bf16.h>
#include <stdint.h>

// Problem dims (fixed by reference): x (4,2048,4096) f32, W (4096,4096) f32,
// bias (4096) f32, sparsity_scale (4096) f32. Tokens T = 8192.
#define T_TOK 8192
#define K_DIM 4096
#define N_DIM 4096
#define NT 128           // K_DIM / 32  (K-tiles of BK=32)
#define WCONV_BLOCKS 16384   // (4096*4096)/(256*4)

typedef short bf16x8 __attribute__((ext_vector_type(8)));
typedef float f32x4  __attribute__((ext_vector_type(4)));
typedef __attribute__((address_space(3))) char* ldsptr;

// RTNE f32 -> bf16 (bit manipulation; matches numpy/jax casts for finite vals)
__device__ __forceinline__ unsigned short f2bf(float f) {
    uint32_t u = __float_as_uint(f);
    u += 0x7FFFu + ((u >> 16) & 1u);
    return (unsigned short)(u >> 16);
}

// async global->LDS, 16B per lane. LDS dest must be wave-uniform base + lane*16.
__device__ __forceinline__ void gl16(const unsigned short* g, ldsptr l) {
    __builtin_amdgcn_global_load_lds(
        (const __attribute__((address_space(1))) void*)g,
        (__attribute__((address_space(3))) void*)l, 16, 0, 0);
}

// ---------------- kernel 0+1 fused: W f32->bf16  ||  2:4 sparsify + quant ----------
// blocks [0, WCONV_BLOCKS): weight convert; blocks [WCONV_BLOCKS, +T_TOK): sparsequant.
__global__ __launch_bounds__(256) void prep_kernel(
        const float* __restrict__ w, unsigned short* __restrict__ wb,
        const float* __restrict__ x, const float* __restrict__ ss,
        unsigned short* __restrict__ qi, float* __restrict__ scales) {
    const int t = threadIdx.x;
    if (blockIdx.x < WCONV_BLOCKS) {
        int i = (blockIdx.x * 256 + t) * 4;   // 4 floats per thread
        float4 v = *(const float4*)(w + i);
        ushort4 o;
        o.x = f2bf(v.x); o.y = f2bf(v.y); o.z = f2bf(v.z); o.w = f2bf(v.w);
        *(ushort4*)(wb + i) = o;
        return;
    }
    const int row = blockIdx.x - WCONV_BLOCKS;
    const float* xr = x + (size_t)row * K_DIM;

    float xs[16];
    float amax = 0.f;
#pragma unroll
    for (int j = 0; j < 4; ++j) {
        int g = t + 256 * j;                     // group index 0..1023
        float4 v  = ((const float4*)xr)[g];
        float4 sv = ((const float4*)ss)[g];
        float e[4] = { v.x, v.y, v.z, v.w };
        float m[4] = { fabsf(v.x) * sv.x, fabsf(v.y) * sv.y,
                       fabsf(v.z) * sv.z, fabsf(v.w) * sv.w };
#pragma unroll
        for (int a = 0; a < 4; ++a) {
            int cnt = 0;
#pragma unroll
            for (int b = 0; b < 4; ++b) {
                if (b == a) continue;
                // strict-order key (metric, index): matches stable top_k of smallest
                bool less = (m[b] < m[a]) || (m[b] == m[a] && b < a);
                cnt += less ? 1 : 0;
            }
            float kept = (cnt >= 2) ? e[a] : 0.f;   // zero the 2 smallest
            xs[j * 4 + a] = kept;
            amax = fmaxf(amax, fabsf(kept));
        }
    }
#pragma unroll
    for (int off = 32; off >= 1; off >>= 1)
        amax = fmaxf(amax, __shfl_xor(amax, off, 64));
    __shared__ float wm[4];
    int wave = t >> 6, lane = t & 63;
    if (lane == 0) wm[wave] = amax;
    __syncthreads();
    amax = fmaxf(fmaxf(wm[0], wm[1]), fmaxf(wm[2], wm[3]));

    float s = fmaxf(amax, 1e-5f) / 127.0f;   // same f32 ops as reference
    if (t == 0) scales[row] = s;

    unsigned short* qr = qi + (size_t)row * K_DIM;
#pragma unroll
    for (int j = 0; j < 4; ++j) {
        int g = t + 256 * j;
        ushort4 o;
        o.x = f2bf(rintf(xs[j * 4 + 0] / s));    // RTNE div+round, ints exact in bf16
        o.y = f2bf(rintf(xs[j * 4 + 1] / s));
        o.z = f2bf(rintf(xs[j * 4 + 2] / s));
        o.w = f2bf(rintf(xs[j * 4 + 3] / s));
        ((ushort4*)qr)[g] = o;
    }
}

// ------------- kernel 2: 256x256 GEMM, BK=32, 64KiB LDS, 2 blocks/CU -------------
// C[m,n] = scales[m] * sum_k A[m,k]*B[n,k] + bias[n]
// r7 = r6 with the launch-bounds bug fixed: r6's __launch_bounds__(512,4) forced a
// 128-VGPR cap while acc alone is 128 VGPR -> guaranteed scratch spill of the
// accumulator inside the MFMA loop (rule #20 pathology) -> pathological binary.
// (512,2) caps at 256; kernel lands ~116 naturally, so HW occupancy still
// reaches 2 blocks/CU (LDS 64KiB: 2 blocks; VGPR 116: 4 waves/EU) — the TLP
// goal without forcing spills.
// BK 64->32 halves LDS to 64KiB -> TWO blocks/CU (16 waves/CU): cross-block TLP
// hides the barrier/vmcnt stalls the 1-block config exposed (m114 mechanism).
// Same 4-phase quadrant order (0,0),(0,1),(1,1),(1,0), counted lgkm/vmcnt with
// halved counts, st_16x32 swizzle both-sides, 2D-chunked XCD swizzle.
// LDS map (dynamic 64KiB): A[buf][h] @ buf*16384 + h*8192 (half = 128 rows x
// 32 k = 8KB = 8 subtiles of 16x32); B same @ +32768. One gl16 per half-stage.
// Per tile T (buf b), steady state:
//  p1: read bf1(T)[2]; stage A1(T+1)->b^1; lgkm(2) [PF-6 done, bf1 fly];
//      MFMA(0,0) x8; BAR
//  p2: stage B1(T+1)->b^1; lgkm(0) [bf1]; MFMA(0,1) x8; read af-h1(T)[4]; BAR
//  p3: stage A0(T+2)->b;   lgkm(0) [af-h1]; MFMA(1,1) x8; vm(3); BAR
//  p4: stage B0(T+2)->b;   MFMA(1,0) x8; PF next h0 [6 reads]; vm(2); BAR
// vmcnt ledger (1 load/stage; queue at T p3-end = [A0(T+1),B0(T+1),A1(T+1),
// B1(T+1),A0(T+2)]): vm(3) retires A0/B0(T+1) -> p4's PF reads (post-BAR) safe;
// p4 +B0(T+2) -> vm(2) retires A1/B1(T+1) -> T+1's p1/p2 reads safe. Every
// ds_read of DMA'd data sits after a barrier that follows the retiring vmcnt
// in ALL waves (per-wave vmcnt covers only own slice; barrier makes it global).
// Edge: tile NT-2 W3=vm(2), W4=vm(0); tile NT-1 no stages/waits.

#define LREAD(dst, base, imm) \
    asm volatile("ds_read_b128 %0, %1 offset:%2" : "=v"(dst) : "v"(base), "i"(imm))

#define WAIT_LGKM(N) do {                                           \
    asm volatile("s_waitcnt lgkmcnt(%0)" :: "i"(N) : "memory");     \
    __builtin_amdgcn_sched_barrier(0);  /* rule #18 */              \
} while (0)

#define WAIT_VM(N) asm volatile("s_waitcnt vmcnt(%0)" :: "i"(N) : "memory")
#define BAR() __builtin_amdgcn_s_barrier()
#define NOP do {} while (0)

#define STAGE_A(T, H, BUF) \
    gl16(pa + (size_t)(H) * 128 * K_DIM + (size_t)(T) * 32, \
         smem3 + ((BUF) * 16384 + (H) * 8192) + tid * 16)

#define STAGE_B(T, H, BUF) \
    gl16(pb + (size_t)(H) * 128 * K_DIM + (size_t)(T) * 32, \
         smem3 + (32768 + (BUF) * 16384 + (H) * 8192) + tid * 16)

// 4 reads into af[i] (A-half H of BUF)
#define READ_AF(BUF, H) do {                                                     \
    _Pragma("unroll")                                                            \
    for (int i_ = 0; i_ < 4; ++i_)                                               \
        LREAD(af[i_], aB, (BUF) * 16384 + (H) * 8192 + i_ * 1024);               \
} while (0)

// 2 reads into ARR[j] (B-half H of BUF)
#define READ_BF(ARR, BUF, H) do {                                                \
    _Pragma("unroll")                                                            \
    for (int j_ = 0; j_ < 2; ++j_)                                               \
        LREAD(ARR[j_], bB, (BUF) * 16384 + (H) * 8192 + j_ * 1024);              \
} while (0)

// 8-MFMA cluster: quadrant (HA,HB)
#define MFMA_C(HA, HB, BF) do {                                                  \
    __builtin_amdgcn_s_setprio(1);                                               \
    _Pragma("unroll")                                                            \
    for (int i_ = 0; i_ < 4; ++i_)                                               \
      _Pragma("unroll")                                                          \
      for (int j_ = 0; j_ < 2; ++j_)                                             \
        acc[HA][i_][HB][j_] = __builtin_amdgcn_mfma_f32_16x16x32_bf16(           \
            af[i_], BF[j_], acc[HA][i_][HB][j_], 0, 0, 0);                       \
    __builtin_amdgcn_s_setprio(0);                                               \
} while (0)

#define TILE(BUF, S1, S2, S3, S4, PFI, W3, W4) do {                              \
    /* p1: (0,0) on af/bf0 (PF'd in prev p4) */                                  \
    READ_BF(bf1, BUF, 1);                                                        \
    S1;                                                                          \
    WAIT_LGKM(2);                                                                \
    MFMA_C(0, 0, bf0);                                                           \
    BAR();                                                                       \
    /* p2: (0,1) */                                                              \
    S2;                                                                          \
    WAIT_LGKM(0);                                                                \
    MFMA_C(0, 1, bf1);                                                           \
    READ_AF(BUF, 1);                                                             \
    BAR();                                                                       \
    /* p3: (1,1) */                                                              \
    S3;                                                                          \
    WAIT_LGKM(0);                                                                \
    MFMA_C(1, 1, bf1);                                                           \
    W3;                                                                          \
    BAR();                                                                       \
    /* p4: (1,0); PF next tile's h0 frags from buf^1 */                          \
    S4;                                                                          \
    MFMA_C(1, 0, bf0);                                                           \
    if (PFI) { READ_AF((BUF) ^ 1, 0); READ_BF(bf0, (BUF) ^ 1, 0); }              \
    W4;                                                                          \
    BAR();                                                                       \
} while (0)

__global__ __launch_bounds__(512, 2) void gemm256_kernel(
        const unsigned short* __restrict__ A,     // [M,K] bf16 (qi)
        const unsigned short* __restrict__ B,     // [N,K] bf16 (Wb)
        const float* __restrict__ scales,         // [M]
        const float* __restrict__ bias,           // [N]
        float* __restrict__ C) {                  // [M,N] f32
    extern __shared__ char smem[];
    ldsptr smem3 = (ldsptr)smem;

    const int tid = threadIdx.x;

    // 2D-chunked bijective XCD swizzle (r4-proven): 8 XCDs as 4x2 chunks of 8x8
    // tiles -> per-XCD streams one 16MB A-panel + 16MB B-panel.
    const int wg   = blockIdx.x;
    const int xcd  = wg & 7;
    const int idx  = wg >> 3;                 // 0..63 within chunk
    const int tm   = (xcd >> 1) * 8 + (idx & 7);    // 0..31
    const int tn   = (xcd & 1) * 8 + (idx >> 3);    // 0..15
    const int tmBase = tm * 256, tnBase = tn * 256;

    // staging source decomposition: thread tid's 16B slot in an 8KB half holds
    // subtile tid>>6, row16 (tid>>2)&15, phys k-granule tid&3; logical k-granule
    // = phys ^ (2*bit3(row16)) -> pre-swizzled source column.
    const int r0   = ((tid >> 6) << 4) + ((tid >> 2) & 15);       // 0..127
    const int kk0  = ((tid & 3) * 8) ^ (((tid >> 5) & 1) << 4);   // pre-swizzled k
    const unsigned short* pa = A + (size_t)(tmBase + r0) * K_DIM + kk0;
    const unsigned short* pb = B + (size_t)(tnBase + r0) * K_DIM + kk0;

    // ds_read lane bases (loop-invariant; st_16x32 XOR folded in once)
    const int lane = tid & 63, wave = tid >> 6;
    const int wr = wave >> 2, wc = wave & 3;            // 2M x 4N waves
    const int laneoff = (lane & 15) * 64 +
        ((((lane >> 4) * 8) ^ (((lane >> 3) & 1) << 4)) << 1);
    ldsptr aB = smem3 + wr * 4096 + laneoff;            // + imm: buf*16384+h*8192+i*1024
    ldsptr bB = smem3 + 32768 + wc * 2048 + laneoff;    // + imm: buf*16384+h*8192+j*1024

    bf16x8 af[4], bf0[2], bf1[2];
    f32x4 acc[2][4][2][2];
    const f32x4 z = { 0.f, 0.f, 0.f, 0.f };
#pragma unroll
    for (int a0 = 0; a0 < 2; ++a0)
#pragma unroll
      for (int a1 = 0; a1 < 4; ++a1)
#pragma unroll
        for (int a2 = 0; a2 < 2; ++a2)
#pragma unroll
          for (int a3 = 0; a3 < 2; ++a3) acc[a0][a1][a2][a3] = z;

    // prologue: stage tile0 (A0,B0,A1,B1)->buf0, tile1 (A0,B0)->buf1 (6 loads).
    // vm(2): tile0's 4 halves landed, A0(1)/B0(1) in flight.
    STAGE_A(0, 0, 0); STAGE_B(0, 0, 0); STAGE_A(0, 1, 0); STAGE_B(0, 1, 0);
    STAGE_A(1, 0, 1); STAGE_B(1, 0, 1);
    WAIT_VM(2);
    BAR();
    READ_AF(0, 0);          // af(0) h0: 4 reads
    READ_BF(bf0, 0, 0);     // bf0(0) h0: 2 reads

    // steady tiles 0..NT-3 (pairs: buf 0 then buf 1)
    for (int t = 0; t < NT - 2; t += 2) {
        TILE(0, STAGE_A(t + 1, 1, 1), STAGE_B(t + 1, 1, 1),
                STAGE_A(t + 2, 0, 0), STAGE_B(t + 2, 0, 0),
                1, WAIT_VM(3), WAIT_VM(2));
        TILE(1, STAGE_A(t + 2, 1, 0), STAGE_B(t + 2, 1, 0),
                STAGE_A(t + 3, 0, 1), STAGE_B(t + 3, 0, 1),
                1, WAIT_VM(3), WAIT_VM(2));
    }
    // tile NT-2 (buf 0): only A1/B1(NT-1) remain to stage; drain 2->0.
    TILE(0, STAGE_A(NT - 1, 1, 1), STAGE_B(NT - 1, 1, 1), NOP, NOP,
            1, WAIT_VM(2), WAIT_VM(0));
    // tile NT-1 (buf 1): nothing to stage or prefetch beyond.
    TILE(1, NOP, NOP, NOP, NOP, 0, NOP, NOP);

    // epilogue: D row = (lane>>4)*4+reg (A side), col = lane&15 (B side)
#pragma unroll
    for (int ha = 0; ha < 2; ++ha)
#pragma unroll
      for (int i = 0; i < 4; ++i) {
        const int rbase = tmBase + ha * 128 + wr * 64 + i * 16 + (lane >> 4) * 4;
        float sc[4];
#pragma unroll
        for (int r = 0; r < 4; ++r) sc[r] = scales[rbase + r];
#pragma unroll
        for (int hb = 0; hb < 2; ++hb)
#pragma unroll
          for (int j = 0; j < 2; ++j) {
            const int col = tnBase + hb * 128 + wc * 32 + j * 16 + (lane & 15);
            const float bb = bias[col];
#pragma unroll
            for (int r = 0; r < 4; ++r)
                C[(size_t)(rbase + r) * N_DIM + col] = sc[r] * acc[ha][i][hb][j][r] + bb;
          }
      }
}

extern "C" void kernel_launch(void* const* d_in, const int* in_sizes, int n_in,
                              void* d_out, int out_size, void* d_ws, size_t ws_size,
                              hipStream_t stream) {
    const float* x    = (const float*)d_in[0];   // (4,2048,4096)
    const float* w    = (const float*)d_in[1];   // (4096,4096)
    const float* bias = (const float*)d_in[2];   // (1,4096)
    const float* ss   = (const float*)d_in[3];   // (1,4096)
    float* out = (float*)d_out;

    // workspace layout: qi bf16 [8192*4096] | scales f32 [8192] | Wb bf16 [4096*4096]
    unsigned short* qi = (unsigned short*)d_ws;
    float* scales = (float*)((char*)d_ws + (size_t)T_TOK * K_DIM * 2);
    unsigned short* wb = (unsigned short*)((char*)d_ws + (size_t)T_TOK * K_DIM * 2 + T_TOK * 4);

    // 64 KiB dynamic LDS: raise the cap (unconditional — r1/r2/r4/r5-proven form).
    (void)hipFuncSetAttribute(reinterpret_cast<const void*>(gemm256_kernel),
                              hipFuncAttributeMaxDynamicSharedMemorySize, 65536);

    prep_kernel<<<WCONV_BLOCKS + T_TOK, 256, 0, stream>>>(w, wb, x, ss, qi, scales);
    gemm256_kernel<<<dim3(512), dim3(512), 65536, stream>>>(qi, wb, scales, bias, out);
}